// Round 3
// baseline (1022.126 us; speedup 1.0000x reference)
//
#include <hip/hip_runtime.h>
#include <cstdint>
#include <cstddef>

#define T_DIM 4
#define B_DIM 32
#define C_DIM 256
#define N_DIM 1024
#define NHEAD 8
#define DHEAD 32
#define NWRD 32   // N/32 bit-words per row

// LIF step, exact reference rounding: v += (x-v)/2; s = v>=vth; hard reset.
__device__ __forceinline__ float lif_step(float& v, float x, float vth) {
    v = __fadd_rn(v, __fmul_rn(__fsub_rn(x, v), 0.5f));
    const float s = (v >= vth) ? 1.0f : 0.0f;
    if (s != 0.0f) v = 0.0f;
    return s;
}

// async global->LDS, 16B per lane. LDS dest = wave-uniform base + lane*16.
__device__ __forceinline__ void async_copy16(const float* g, float* l) {
    __builtin_amdgcn_global_load_lds(
        (const __attribute__((address_space(1))) unsigned int*)g,
        (__attribute__((address_space(3))) unsigned int*)l, 16, 0, 0);
}

// 16 fp32 FMAs, strict k-ascending chains per output (bit-stable vs reference)
#define FMA16(a, bv)                          \
    acc[ 0] = fmaf(a.x, bv.x, acc[ 0]);       \
    acc[ 1] = fmaf(a.x, bv.y, acc[ 1]);       \
    acc[ 2] = fmaf(a.x, bv.z, acc[ 2]);       \
    acc[ 3] = fmaf(a.x, bv.w, acc[ 3]);       \
    acc[ 4] = fmaf(a.y, bv.x, acc[ 4]);       \
    acc[ 5] = fmaf(a.y, bv.y, acc[ 5]);       \
    acc[ 6] = fmaf(a.y, bv.z, acc[ 6]);       \
    acc[ 7] = fmaf(a.y, bv.w, acc[ 7]);       \
    acc[ 8] = fmaf(a.z, bv.x, acc[ 8]);       \
    acc[ 9] = fmaf(a.z, bv.y, acc[ 9]);       \
    acc[10] = fmaf(a.z, bv.z, acc[10]);       \
    acc[11] = fmaf(a.z, bv.w, acc[11]);       \
    acc[12] = fmaf(a.w, bv.x, acc[12]);       \
    acc[13] = fmaf(a.w, bv.y, acc[13]);       \
    acc[14] = fmaf(a.w, bv.z, acc[14]);       \
    acc[15] = fmaf(a.w, bv.w, acc[15]);

// Pre-transpose: wqk_t[k][h*64+j] = (j<32 ? qw[h*32+j][k] : kw[h*32+j-32][k])
//                p_t[k][c] = pw[c][k]
__global__ __launch_bounds__(256) void k_transpose(
    const float* __restrict__ qw, const float* __restrict__ kw,
    const float* __restrict__ pw, float* __restrict__ wqk_t,
    float* __restrict__ p_t)
{
    const int i = blockIdx.x * 256 + threadIdx.x;
    if (i < C_DIM * 512) {
        const int k = i >> 9, col = i & 511;
        const int h = col >> 6, j = col & 63;
        wqk_t[i] = (j < 32) ? qw[(size_t)(h * 32 + j) * C_DIM + k]
                            : kw[(size_t)(h * 32 + j - 32) * C_DIM + k];
    } else {
        const int i2 = i - C_DIM * 512;            // < 65536
        const int k = i2 >> 8, c = i2 & 255;
        p_t[i2] = pw[(size_t)c * C_DIM + k];
    }
}

// K1: Q/K GEMM + BN + LIF + head-sum + attn LIF -> bit-packed x_one
// grid (NHEAD, N/64, B), block 256. Weights (256x64) resident in LDS;
// x streamed as BK=32 chunks, double-buffered via global_load_lds.
__global__ __launch_bounds__(256) void k_qk(
    const float* __restrict__ x, const float* __restrict__ wqk,   // [256][512]
    const float* __restrict__ qg, const float* __restrict__ qbeta,
    const float* __restrict__ qmean, const float* __restrict__ qvar,
    const float* __restrict__ kg, const float* __restrict__ kbeta,
    const float* __restrict__ kmean, const float* __restrict__ kvar,
    uint32_t* __restrict__ xbits)
{
    __shared__ float w_lds[C_DIM * 64];     // [k][m] resident, 64 KB
    __shared__ float x_lds[2][32 * 64];     // dbuf [k-chunk][n], 2x8 KB
    // epilogue scratch aliased onto x_lds[0] (free during epilogue)
    float*    qsum_lds = &x_lds[0][0];      // 64 floats
    float*    attn_lds = &x_lds[0][64];     // 64 floats
    uint32_t* pack_lds = (uint32_t*)&x_lds[0][128];  // 64 words

    const int tid = threadIdx.x;
    const int h = blockIdx.x, nt = blockIdx.y, b = blockIdx.z;
    const int n0g = nt * 64;

    const int  mg   = tid >> 4;
    const int  m0   = mg << 2;
    const int  n0   = (tid & 15) << 2;
    const bool is_q = (mg < 8);

    float inv4[4], bias4[4];
    {
        const float* g  = is_q ? qg    : kg;
        const float* be = is_q ? qbeta : kbeta;
        const float* me = is_q ? qmean : kmean;
        const float* va = is_q ? qvar  : kvar;
        const int cb = h * DHEAD + (is_q ? m0 : (m0 - 32));
        #pragma unroll
        for (int i = 0; i < 4; i++) {
            const float iv = __fdiv_rn(g[cb + i], __fsqrt_rn(__fadd_rn(va[cb + i], 1e-5f)));
            inv4[i]  = iv;
            bias4[i] = __fsub_rn(be[cb + i], __fmul_rn(me[cb + i], iv));
        }
    }

    const int wid = tid >> 6, lane = tid & 63;
    const int lr  = lane >> 4;
    const int lc  = (lane & 15) << 2;

    // resident weight tile: wave wid loads rows wid*64..wid*64+63
    {
        const float* wg = wqk + (size_t)(wid * 64 + lr) * 512 + h * 64 + lc;
        float* wl = w_lds + (size_t)(wid * 64) * 64;
        #pragma unroll
        for (int j = 0; j < 16; j++)
            async_copy16(wg + (size_t)(j * 4) * 512, wl + j * 256);
        // drained by the first chunk barrier
    }

    float vstate[16];
    #pragma unroll
    for (int i = 0; i < 16; i++) vstate[i] = 0.0f;
    float v_attn = 0.0f;

    for (int t = 0; t < T_DIM; ++t) {
        float acc[16];
        #pragma unroll
        for (int i = 0; i < 16; i++) acc[i] = 0.0f;

        // this thread stages x rows (wid*8 + lr) within each chunk
        const float* xg = x + ((size_t)(t * B_DIM + b) * C_DIM + wid * 8 + lr) * N_DIM
                          + n0g + lc;

        // stage chunk 0 into buf0 (prev t's scratch readers joined by epilogue barrier)
        async_copy16(xg,                       x_lds[0] + wid * 512);
        async_copy16(xg + (size_t)4 * N_DIM,   x_lds[0] + wid * 512 + 256);

        for (int c = 0; c < 8; ++c) {
            __syncthreads();    // drains stage(c) (+w on t=0); joins readers of buf[(c+1)&1]
            if (c + 1 < 8) {
                const size_t ko = (size_t)((c + 1) * 32);
                float* dst = x_lds[(c + 1) & 1] + wid * 512;
                async_copy16(xg + (ko    ) * N_DIM, dst);
                async_copy16(xg + (ko + 4) * N_DIM, dst + 256);
            }
            const float* xl = x_lds[c & 1];
            const float* wl = w_lds + (size_t)(c * 32) * 64;
            #pragma unroll 4
            for (int k = 0; k < 32; k++) {
                const float4 a  = *(const float4*)(wl + k * 64 + m0);
                const float4 bv = *(const float4*)(xl + k * 64 + n0);
                FMA16(a, bv)
            }
        }

        // BN + LIF (registers only)
        float sarr[16];
        #pragma unroll
        for (int i = 0; i < 4; i++) {
            #pragma unroll
            for (int j = 0; j < 4; j++) {
                const float y = __fadd_rn(__fmul_rn(acc[i * 4 + j], inv4[i]), bias4[i]);
                sarr[i * 4 + j] = lif_step(vstate[i * 4 + j], y, 1.0f);
            }
        }

        // scratch lives in buf0; all waves are past fma(chunk 6) (barrier c=7) so buf0 free
        if (tid < 64) { qsum_lds[tid] = 0.0f; pack_lds[tid] = 0u; }
        __syncthreads();

        if (is_q) {   // head-sum of q spikes (integer-valued -> exact in any order)
            #pragma unroll
            for (int j = 0; j < 4; j++) {
                const float cs = sarr[j] + sarr[4 + j] + sarr[8 + j] + sarr[12 + j];
                atomicAdd(&qsum_lds[n0 + j], cs);
            }
        }
        __syncthreads();
        if (tid < 64) attn_lds[tid] = lif_step(v_attn, qsum_lds[tid], 0.5f);
        __syncthreads();

        if (!is_q) {  // x_one = attn * k_spikes, bit-packed
            #pragma unroll
            for (int i = 0; i < 4; i++) {
                uint32_t nib = 0;
                #pragma unroll
                for (int j = 0; j < 4; j++) {
                    if (sarr[i * 4 + j] != 0.0f && attn_lds[n0 + j] != 0.0f)
                        nib |= (1u << j);
                }
                if (nib)
                    atomicOr(&pack_lds[((m0 - 32) + i) * 2 + (n0 >> 5)], nib << (n0 & 31));
            }
        }
        __syncthreads();
        if (tid < 64) {
            const int row = tid >> 1, word = tid & 1;
            const int c = h * DHEAD + row;
            xbits[((size_t)(t * B_DIM + b) * C_DIM + c) * NWRD + (n0g >> 5) + word]
                = pack_lds[tid];
        }
        __syncthreads();   // protect scratch (buf0) before next t's chunk-0 stage
    }
}

// K2: projection GEMM (bit-packed binary input) + bias + BN + LIF -> spikes
// grid (C/64, N/64, B), block 256. Weights resident; x bits unpacked into
// double-buffered BK=32 chunks, bit-word pipelined through a register.
__global__ __launch_bounds__(256) void k_proj(
    const uint32_t* __restrict__ xbits, const float* __restrict__ pt,  // [256][256]
    const float* __restrict__ pbias, const float* __restrict__ pg,
    const float* __restrict__ pbeta, const float* __restrict__ pmean,
    const float* __restrict__ pvar, float* __restrict__ out)
{
    __shared__ float w_lds[C_DIM * 64];     // [k][c-tile] resident, 64 KB
    __shared__ float x_lds[2][32 * 64];     // dbuf, 2x8 KB

    const int tid = threadIdx.x;
    const int mt = blockIdx.x, nt = blockIdx.y, b = blockIdx.z;
    const int n0g = nt * 64;
    const int c0  = mt * 64;

    const int mg = tid >> 4, m0 = mg << 2;
    const int n0 = (tid & 15) << 2;

    float inv4[4], bias4[4], pb4[4];
    #pragma unroll
    for (int i = 0; i < 4; i++) {
        const int c = c0 + m0 + i;
        const float iv = __fdiv_rn(pg[c], __fsqrt_rn(__fadd_rn(pvar[c], 1e-5f)));
        inv4[i]  = iv;
        bias4[i] = __fsub_rn(pbeta[c], __fmul_rn(pmean[c], iv));
        pb4[i]   = pbias[c];
    }

    const int wid = tid >> 6, lane = tid & 63;
    const int lr  = lane >> 4;
    const int lc  = (lane & 15) << 2;

    // resident weight tile
    {
        const float* wg = pt + (size_t)(wid * 64 + lr) * 256 + c0 + lc;
        float* wl = w_lds + (size_t)(wid * 64) * 64;
        #pragma unroll
        for (int j = 0; j < 16; j++)
            async_copy16(wg + (size_t)(j * 4) * 256, wl + j * 256);
    }

    // unpack geometry: thread covers chunk-row r, 8 cols starting gg*8
    const int r  = tid >> 3, gg = tid & 7;
    const int shf = (gg & 3) * 8;
    float* xw0 = &x_lds[0][r * 64 + gg * 8];
    float* xw1 = &x_lds[1][r * 64 + gg * 8];

    float vstate[16];
    #pragma unroll
    for (int i = 0; i < 16; i++) vstate[i] = 0.0f;

    for (int t = 0; t < T_DIM; ++t) {
        float acc[16];
        #pragma unroll
        for (int i = 0; i < 16; i++) acc[i] = 0.0f;

        const uint32_t* xg = xbits + ((size_t)(t * B_DIM + b) * C_DIM + r) * NWRD
                             + (n0g >> 5) + (gg >> 2);

        // pipeline: u holds bit-word for the chunk about to be unpacked
        uint32_t u = xg[0];
        {   // unpack chunk 0 into buf0 (all waves past prev-t fma(6); buf0 free)
            const uint32_t bits = (u >> shf) & 0xffu;
            float4 f0, f1;
            f0.x = (bits & 1u)        ? 1.0f : 0.0f;
            f0.y = ((bits >> 1) & 1u) ? 1.0f : 0.0f;
            f0.z = ((bits >> 2) & 1u) ? 1.0f : 0.0f;
            f0.w = ((bits >> 3) & 1u) ? 1.0f : 0.0f;
            f1.x = ((bits >> 4) & 1u) ? 1.0f : 0.0f;
            f1.y = ((bits >> 5) & 1u) ? 1.0f : 0.0f;
            f1.z = ((bits >> 6) & 1u) ? 1.0f : 0.0f;
            f1.w = ((bits >> 7) & 1u) ? 1.0f : 0.0f;
            *(float4*)xw0       = f0;
            *(float4*)(xw0 + 4) = f1;
        }
        u = xg[(size_t)32 * NWRD];   // word for chunk 1

        for (int c = 0; c < 8; ++c) {
            __syncthreads();   // lgkm drained (unpack writes); joins readers
            if (c + 1 < 8) {
                const uint32_t bits = (u >> shf) & 0xffu;
                float4 f0, f1;
                f0.x = (bits & 1u)        ? 1.0f : 0.0f;
                f0.y = ((bits >> 1) & 1u) ? 1.0f : 0.0f;
                f0.z = ((bits >> 2) & 1u) ? 1.0f : 0.0f;
                f0.w = ((bits >> 3) & 1u) ? 1.0f : 0.0f;
                f1.x = ((bits >> 4) & 1u) ? 1.0f : 0.0f;
                f1.y = ((bits >> 5) & 1u) ? 1.0f : 0.0f;
                f1.z = ((bits >> 6) & 1u) ? 1.0f : 0.0f;
                f1.w = ((bits >> 7) & 1u) ? 1.0f : 0.0f;
                float* xw = ((c + 1) & 1) ? xw1 : xw0;
                *(float4*)xw       = f0;
                *(float4*)(xw + 4) = f1;
                if (c + 2 < 8) u = xg[(size_t)(c + 2) * 32 * NWRD];
            }
            const float* xl = x_lds[c & 1];
            const float* wl = w_lds + (size_t)(c * 32) * 64;
            #pragma unroll 4
            for (int k = 0; k < 32; k++) {
                const float4 a  = *(const float4*)(wl + k * 64 + m0);
                const float4 bv = *(const float4*)(xl + k * 64 + n0);
                FMA16(a, bv)
            }
        }

        #pragma unroll
        for (int i = 0; i < 4; i++) {
            float s4[4];
            #pragma unroll
            for (int j = 0; j < 4; j++) {
                float y = __fadd_rn(acc[i * 4 + j], pb4[i]);
                y = __fadd_rn(__fmul_rn(y, inv4[i]), bias4[i]);
                s4[j] = lif_step(vstate[i * 4 + j], y, 1.0f);
            }
            const int c = c0 + m0 + i;
            float4 o4;
            o4.x = s4[0]; o4.y = s4[1]; o4.z = s4[2]; o4.w = s4[3];
            *(float4*)(out + ((size_t)(t * B_DIM + b) * C_DIM + c) * N_DIM + n0g + n0) = o4;
        }
    }
}

extern "C" void kernel_launch(void* const* d_in, const int* in_sizes, int n_in,
                              void* d_out, int out_size, void* d_ws, size_t ws_size,
                              hipStream_t stream) {
    const float* x    = (const float*)d_in[0];
    const float* q_w  = (const float*)d_in[1];
    const float* q_g  = (const float*)d_in[2];
    const float* q_b  = (const float*)d_in[3];
    const float* q_m  = (const float*)d_in[4];
    const float* q_v  = (const float*)d_in[5];
    const float* k_w  = (const float*)d_in[6];
    const float* k_g  = (const float*)d_in[7];
    const float* k_b  = (const float*)d_in[8];
    const float* k_m  = (const float*)d_in[9];
    const float* k_v  = (const float*)d_in[10];
    const float* p_w  = (const float*)d_in[11];
    const float* p_b  = (const float*)d_in[12];
    const float* p_g  = (const float*)d_in[13];
    const float* p_be = (const float*)d_in[14];
    const float* p_m  = (const float*)d_in[15];
    const float* p_v  = (const float*)d_in[16];

    // ws layout: wqk_t 512KB | p_t 256KB | xbits 4MB
    float*    wqk_t = (float*)d_ws;
    float*    p_t   = (float*)((char*)d_ws + 524288);
    uint32_t* xbits = (uint32_t*)((char*)d_ws + 786432);
    float*    out   = (float*)d_out;

    k_transpose<<<768, 256, 0, stream>>>(q_w, k_w, p_w, wqk_t, p_t);

    dim3 g1(NHEAD, N_DIM / 64, B_DIM);
    k_qk<<<g1, 256, 0, stream>>>(x, wqk_t, q_g, q_b, q_m, q_v,
                                 k_g, k_b, k_m, k_v, xbits);

    dim3 g2(C_DIM / 64, N_DIM / 64, B_DIM);
    k_proj<<<g2, 256, 0, stream>>>(xbits, p_t, p_b, p_g, p_be, p_m, p_v, out);
}

// Round 4
// 877.586 us; speedup vs baseline: 1.1647x; 1.1647x over previous
//
#include <hip/hip_runtime.h>
#include <cstdint>
#include <cstddef>

#define T_DIM 4
#define B_DIM 32
#define C_DIM 256
#define N_DIM 1024
#define NHEAD 8
#define DHEAD 32
#define NWRD 32   // N/32 bit-words per row

// LIF step, exact reference rounding: v += (x-v)/2; s = v>=vth; hard reset.
__device__ __forceinline__ float lif_step(float& v, float x, float vth) {
    v = __fadd_rn(v, __fmul_rn(__fsub_rn(x, v), 0.5f));
    const float s = (v >= vth) ? 1.0f : 0.0f;
    if (s != 0.0f) v = 0.0f;
    return s;
}

// async global->LDS, 16B per lane. LDS dest = wave-uniform base + lane*16.
__device__ __forceinline__ void async_copy16(const float* g, float* l) {
    __builtin_amdgcn_global_load_lds(
        (const __attribute__((address_space(1))) unsigned int*)g,
        (__attribute__((address_space(3))) unsigned int*)l, 16, 0, 0);
}

// one a-row times 8 cols (two float4 col-quads), strict k-ascending chains
#define FMA_ROW(r, av)                                \
    acc[(r)*8+0] = fmaf(av, b0.x, acc[(r)*8+0]);      \
    acc[(r)*8+1] = fmaf(av, b0.y, acc[(r)*8+1]);      \
    acc[(r)*8+2] = fmaf(av, b0.z, acc[(r)*8+2]);      \
    acc[(r)*8+3] = fmaf(av, b0.w, acc[(r)*8+3]);      \
    acc[(r)*8+4] = fmaf(av, b1.x, acc[(r)*8+4]);      \
    acc[(r)*8+5] = fmaf(av, b1.y, acc[(r)*8+5]);      \
    acc[(r)*8+6] = fmaf(av, b1.z, acc[(r)*8+6]);      \
    acc[(r)*8+7] = fmaf(av, b1.w, acc[(r)*8+7]);

// Pre-transpose: wqk_t[k][h*64+j] = (j<32 ? qw[h*32+j][k] : kw[h*32+j-32][k])
//                p_t[k][c] = pw[c][k]
__global__ __launch_bounds__(256) void k_transpose(
    const float* __restrict__ qw, const float* __restrict__ kw,
    const float* __restrict__ pw, float* __restrict__ wqk_t,
    float* __restrict__ p_t)
{
    const int i = blockIdx.x * 256 + threadIdx.x;
    if (i < C_DIM * 512) {
        const int k = i >> 9, col = i & 511;
        const int h = col >> 6, j = col & 63;
        wqk_t[i] = (j < 32) ? qw[(size_t)(h * 32 + j) * C_DIM + k]
                            : kw[(size_t)(h * 32 + j - 32) * C_DIM + k];
    } else {
        const int i2 = i - C_DIM * 512;            // < 65536
        const int k = i2 >> 8, c = i2 & 255;
        p_t[i2] = pw[(size_t)c * C_DIM + k];
    }
}

// K1: Q/K GEMM + BN + LIF + head-sum + attn LIF -> bit-packed x_one
// grid (NHEAD, N/128, B), block 256. Block tile 64m x 128n, BK=32,
// thread tile 4 rows x 8 cols (col quads at n0 and 64+n0).
__global__ __launch_bounds__(256, 4) void k_qk(
    const float* __restrict__ x, const float* __restrict__ wqk,   // [256][512]
    const float* __restrict__ qg, const float* __restrict__ qbeta,
    const float* __restrict__ qmean, const float* __restrict__ qvar,
    const float* __restrict__ kg, const float* __restrict__ kbeta,
    const float* __restrict__ kmean, const float* __restrict__ kvar,
    uint32_t* __restrict__ xbits)
{
    __shared__ float w_lds[32 * 64];    // [k][m] 8 KB
    __shared__ float x_lds[32 * 128];   // [k][n] 16 KB
    // epilogue scratch aliased onto x_lds (free after last chunk's barrier)
    float*    qsum_lds = x_lds;                     // 128 f
    float*    attn_lds = x_lds + 128;               // 128 f
    uint32_t* pack_lds = (uint32_t*)(x_lds + 256);  // 128 words

    const int tid = threadIdx.x;
    const int h = blockIdx.x, nt = blockIdx.y, b = blockIdx.z;
    const int n0g = nt * 128;

    const int  mg = tid >> 4;        // 0..15: rows mg*4..+3 (mg<8 => q)
    const int  m0 = mg << 2;
    const int  ng = tid & 15;
    const int  n0 = ng << 2;         // col quad A; quad B = 64+n0
    const bool is_q = (mg < 8);

    float inv4[4], bias4[4];
    {
        const float* g  = is_q ? qg    : kg;
        const float* be = is_q ? qbeta : kbeta;
        const float* me = is_q ? qmean : kmean;
        const float* va = is_q ? qvar  : kvar;
        const int cb = h * DHEAD + (is_q ? m0 : (m0 - 32));
        #pragma unroll
        for (int i = 0; i < 4; i++) {
            const float iv = __fdiv_rn(g[cb + i], __fsqrt_rn(__fadd_rn(va[cb + i], 1e-5f)));
            inv4[i]  = iv;
            bias4[i] = __fsub_rn(be[cb + i], __fmul_rn(me[cb + i], iv));
        }
    }

    // staging geometry (flat LDS offset = round*1024 + tid*4 floats)
    const int wk = tid >> 4;            // w: k = kk + round*16 + wk, m = wm
    const int wm = (tid & 15) << 2;
    const int xk = tid >> 5;            // x: k = kk + round*8 + xk, col = xc
    const int xc = (tid & 31) << 2;
    const float* wgp = wqk + h * 64 + wm;

    float vstate[32];
    #pragma unroll
    for (int i = 0; i < 32; i++) vstate[i] = 0.0f;
    float v_attn = 0.0f;                // used by tid<128 (one attn col each)

    for (int t = 0; t < T_DIM; ++t) {
        float acc[32];
        #pragma unroll
        for (int i = 0; i < 32; i++) acc[i] = 0.0f;

        const float* xgp = x + (size_t)(t * B_DIM + b) * C_DIM * N_DIM + n0g + xc;

        for (int c = 0; c < 8; ++c) {
            const int kk = c * 32;
            __syncthreads();    // prior readers of w_lds/x_lds (or scratch) done
            async_copy16(wgp + (size_t)(kk      + wk) * 512, w_lds + tid * 4);
            async_copy16(wgp + (size_t)(kk + 16 + wk) * 512, w_lds + 1024 + tid * 4);
            #pragma unroll
            for (int r = 0; r < 4; r++)
                async_copy16(xgp + (size_t)(kk + r * 8 + xk) * N_DIM,
                             x_lds + r * 1024 + tid * 4);
            __syncthreads();    // drain
            #pragma unroll 4
            for (int k = 0; k < 32; k++) {
                const float4 a  = *(const float4*)(w_lds + k * 64 + m0);
                const float4 b0 = *(const float4*)(x_lds + k * 128 + n0);
                const float4 b1 = *(const float4*)(x_lds + k * 128 + 64 + n0);
                FMA_ROW(0, a.x)
                FMA_ROW(1, a.y)
                FMA_ROW(2, a.z)
                FMA_ROW(3, a.w)
            }
        }

        // BN + LIF; spikes overwrite acc (register reuse)
        #pragma unroll
        for (int r = 0; r < 4; r++) {
            #pragma unroll
            for (int j = 0; j < 8; j++) {
                const float y = __fadd_rn(__fmul_rn(acc[r * 8 + j], inv4[r]), bias4[r]);
                acc[r * 8 + j] = lif_step(vstate[r * 8 + j], y, 1.0f);
            }
        }

        __syncthreads();   // all FMA readers done -> x_lds reusable as scratch
        if (tid < 128) qsum_lds[tid] = 0.0f; else pack_lds[tid - 128] = 0u;
        __syncthreads();

        if (is_q) {   // head-sum of q spikes (integer-valued -> exact any order)
            #pragma unroll
            for (int j = 0; j < 8; j++) {
                const int col = (j < 4) ? (n0 + j) : (64 + n0 + (j - 4));
                const float cs = acc[j] + acc[8 + j] + acc[16 + j] + acc[24 + j];
                atomicAdd(&qsum_lds[col], cs);
            }
        }
        __syncthreads();
        if (tid < 128) attn_lds[tid] = lif_step(v_attn, qsum_lds[tid], 0.5f);
        __syncthreads();

        if (!is_q) {  // x_one = attn * k_spikes, bit-packed
            #pragma unroll
            for (int r = 0; r < 4; r++) {
                const int krow = (mg - 8) * 4 + r;
                #pragma unroll
                for (int ci = 0; ci < 2; ci++) {
                    uint32_t nib = 0;
                    #pragma unroll
                    for (int jj = 0; jj < 4; jj++) {
                        const int col = ci * 64 + n0 + jj;
                        if (acc[r * 8 + ci * 4 + jj] != 0.0f && attn_lds[col] != 0.0f)
                            nib |= (1u << jj);
                    }
                    if (nib) {
                        const int word = ci * 2 + (ng >> 3);
                        const int shf  = (ng & 7) * 4;
                        atomicOr(&pack_lds[krow * 4 + word], nib << shf);
                    }
                }
            }
        }
        __syncthreads();
        if (tid < 128) {
            const int krow = tid >> 2, word = tid & 3;
            const int ch = h * DHEAD + krow;
            xbits[((size_t)(t * B_DIM + b) * C_DIM + ch) * NWRD + nt * 4 + word]
                = pack_lds[tid];
        }
        // next t's chunk-0 barrier protects scratch readers
    }
}

// K2: projection GEMM (bit-packed binary input) + bias + BN + LIF -> spikes
// grid (C/64, N/128, B), block 256. Same 64m x 128n tile; bit-words for the
// next chunk prefetched into registers during current chunk's FMA.
__global__ __launch_bounds__(256, 4) void k_proj(
    const uint32_t* __restrict__ xbits, const float* __restrict__ pt,  // [256][256]
    const float* __restrict__ pbias, const float* __restrict__ pg,
    const float* __restrict__ pbeta, const float* __restrict__ pmean,
    const float* __restrict__ pvar, float* __restrict__ out)
{
    __shared__ float w_lds[32 * 64];
    __shared__ float x_lds[32 * 128];

    const int tid = threadIdx.x;
    const int mt = blockIdx.x, nt = blockIdx.y, b = blockIdx.z;
    const int n0g = nt * 128;
    const int c0  = mt * 64;

    const int mg = tid >> 4, m0 = mg << 2;
    const int ng = tid & 15, n0 = ng << 2;

    float inv4[4], bias4[4], pb4[4];
    #pragma unroll
    for (int i = 0; i < 4; i++) {
        const int ch = c0 + m0 + i;
        const float iv = __fdiv_rn(pg[ch], __fsqrt_rn(__fadd_rn(pvar[ch], 1e-5f)));
        inv4[i]  = iv;
        bias4[i] = __fsub_rn(pbeta[ch], __fmul_rn(pmean[ch], iv));
        pb4[i]   = pbias[ch];
    }

    const int wk = tid >> 4;
    const int wm = (tid & 15) << 2;
    const float* wgp = pt + c0 + wm;

    // bit-word geometry: round r covers k-row r*8+(tid>>5), cols (tid&31)*4..+3
    const int usel = nt * 4 + ((tid & 31) >> 3);
    const int shf  = (tid & 7) * 4;
    const int urow = tid >> 5;

    float vstate[32];
    #pragma unroll
    for (int i = 0; i < 32; i++) vstate[i] = 0.0f;

    for (int t = 0; t < T_DIM; ++t) {
        float acc[32];
        #pragma unroll
        for (int i = 0; i < 32; i++) acc[i] = 0.0f;

        const uint32_t* xg = xbits + (size_t)(t * B_DIM + b) * C_DIM * NWRD;

        uint32_t u[4];
        #pragma unroll
        for (int r = 0; r < 4; r++)
            u[r] = xg[(size_t)(r * 8 + urow) * NWRD + usel];

        for (int c = 0; c < 8; ++c) {
            __syncthreads();    // prior readers done
            // unpack current chunk's bits -> x_lds (contiguous b128 writes)
            #pragma unroll
            for (int r = 0; r < 4; r++) {
                const uint32_t bits = (u[r] >> shf) & 0xFu;
                float4 f;
                f.x = (bits & 1u)        ? 1.0f : 0.0f;
                f.y = ((bits >> 1) & 1u) ? 1.0f : 0.0f;
                f.z = ((bits >> 2) & 1u) ? 1.0f : 0.0f;
                f.w = ((bits >> 3) & 1u) ? 1.0f : 0.0f;
                *(float4*)(x_lds + r * 1024 + tid * 4) = f;
            }
            async_copy16(wgp + (size_t)(c * 32      + wk) * 256, w_lds + tid * 4);
            async_copy16(wgp + (size_t)(c * 32 + 16 + wk) * 256, w_lds + 1024 + tid * 4);
            __syncthreads();    // drain lgkm (unpack) + vmcnt (w stage)
            if (c + 1 < 8) {    // prefetch next chunk's bit-words during FMA
                #pragma unroll
                for (int r = 0; r < 4; r++)
                    u[r] = xg[(size_t)((c + 1) * 32 + r * 8 + urow) * NWRD + usel];
            }
            #pragma unroll 4
            for (int k = 0; k < 32; k++) {
                const float4 a  = *(const float4*)(w_lds + k * 64 + m0);
                const float4 b0 = *(const float4*)(x_lds + k * 128 + n0);
                const float4 b1 = *(const float4*)(x_lds + k * 128 + 64 + n0);
                FMA_ROW(0, a.x)
                FMA_ROW(1, a.y)
                FMA_ROW(2, a.z)
                FMA_ROW(3, a.w)
            }
        }

        #pragma unroll
        for (int r = 0; r < 4; r++) {
            const int ch = c0 + m0 + r;
            float* ob = out + ((size_t)(t * B_DIM + b) * C_DIM + ch) * N_DIM + n0g;
            float4 oA, oB;
            float oAv[4], oBv[4];
            #pragma unroll
            for (int j = 0; j < 8; j++) {
                float y = __fadd_rn(acc[r * 8 + j], pb4[r]);
                y = __fadd_rn(__fmul_rn(y, inv4[r]), bias4[r]);
                const float s = lif_step(vstate[r * 8 + j], y, 1.0f);
                if (j < 4) oAv[j] = s; else oBv[j - 4] = s;
            }
            oA.x = oAv[0]; oA.y = oAv[1]; oA.z = oAv[2]; oA.w = oAv[3];
            oB.x = oBv[0]; oB.y = oBv[1]; oB.z = oBv[2]; oB.w = oBv[3];
            *(float4*)(ob + n0)      = oA;
            *(float4*)(ob + 64 + n0) = oB;
        }
    }
}

extern "C" void kernel_launch(void* const* d_in, const int* in_sizes, int n_in,
                              void* d_out, int out_size, void* d_ws, size_t ws_size,
                              hipStream_t stream) {
    const float* x    = (const float*)d_in[0];
    const float* q_w  = (const float*)d_in[1];
    const float* q_g  = (const float*)d_in[2];
    const float* q_b  = (const float*)d_in[3];
    const float* q_m  = (const float*)d_in[4];
    const float* q_v  = (const float*)d_in[5];
    const float* k_w  = (const float*)d_in[6];
    const float* k_g  = (const float*)d_in[7];
    const float* k_b  = (const float*)d_in[8];
    const float* k_m  = (const float*)d_in[9];
    const float* k_v  = (const float*)d_in[10];
    const float* p_w  = (const float*)d_in[11];
    const float* p_b  = (const float*)d_in[12];
    const float* p_g  = (const float*)d_in[13];
    const float* p_be = (const float*)d_in[14];
    const float* p_m  = (const float*)d_in[15];
    const float* p_v  = (const float*)d_in[16];

    // ws layout: wqk_t 512KB | p_t 256KB | xbits 4MB
    float*    wqk_t = (float*)d_ws;
    float*    p_t   = (float*)((char*)d_ws + 524288);
    uint32_t* xbits = (uint32_t*)((char*)d_ws + 786432);
    float*    out   = (float*)d_out;

    k_transpose<<<768, 256, 0, stream>>>(q_w, k_w, p_w, wqk_t, p_t);

    dim3 g1(NHEAD, N_DIM / 128, B_DIM);
    k_qk<<<g1, 256, 0, stream>>>(x, wqk_t, q_g, q_b, q_m, q_v,
                                 k_g, k_b, k_m, k_v, xbits);

    dim3 g2(C_DIM / 64, N_DIM / 128, B_DIM);
    k_proj<<<g2, 256, 0, stream>>>(xbits, p_t, p_b, p_g, p_be, p_m, p_v, out);
}

// Round 5
// 829.031 us; speedup vs baseline: 1.2329x; 1.0586x over previous
//
#include <hip/hip_runtime.h>
#include <cstdint>
#include <cstddef>

#define T_DIM 4
#define B_DIM 32
#define C_DIM 256
#define N_DIM 1024
#define NHEAD 8
#define DHEAD 32
#define NWRD 32   // N/32 bit-words per row

// LIF step, exact reference rounding: v += (x-v)/2; s = v>=vth; hard reset.
__device__ __forceinline__ float lif_step(float& v, float x, float vth) {
    v = __fadd_rn(v, __fmul_rn(__fsub_rn(x, v), 0.5f));
    const float s = (v >= vth) ? 1.0f : 0.0f;
    if (s != 0.0f) v = 0.0f;
    return s;
}

// async global->LDS, 16B per lane. LDS dest = wave-uniform base + lane*16.
__device__ __forceinline__ void async_copy16(const float* g, float* l) {
    __builtin_amdgcn_global_load_lds(
        (const __attribute__((address_space(1))) unsigned int*)g,
        (__attribute__((address_space(3))) unsigned int*)l, 16, 0, 0);
}

// one a-element times 8 cols (two float4 col-quads), strict k-ascending chains
#define FMA_ROW(r, av)                                \
    acc[(r)*8+0] = fmaf(av, b0.x, acc[(r)*8+0]);      \
    acc[(r)*8+1] = fmaf(av, b0.y, acc[(r)*8+1]);      \
    acc[(r)*8+2] = fmaf(av, b0.z, acc[(r)*8+2]);      \
    acc[(r)*8+3] = fmaf(av, b0.w, acc[(r)*8+3]);      \
    acc[(r)*8+4] = fmaf(av, b1.x, acc[(r)*8+4]);      \
    acc[(r)*8+5] = fmaf(av, b1.y, acc[(r)*8+5]);      \
    acc[(r)*8+6] = fmaf(av, b1.z, acc[(r)*8+6]);      \
    acc[(r)*8+7] = fmaf(av, b1.w, acc[(r)*8+7]);

#define FMA_8x8()        \
    FMA_ROW(0, a0.x)     \
    FMA_ROW(1, a0.y)     \
    FMA_ROW(2, a0.z)     \
    FMA_ROW(3, a0.w)     \
    FMA_ROW(4, a1.x)     \
    FMA_ROW(5, a1.y)     \
    FMA_ROW(6, a1.z)     \
    FMA_ROW(7, a1.w)

// Pre-transpose: wqk_t[k][h*64+j] = (j<32 ? qw[h*32+j][k] : kw[h*32+j-32][k])
//                p_t[k][c] = pw[c][k]
__global__ __launch_bounds__(256) void k_transpose(
    const float* __restrict__ qw, const float* __restrict__ kw,
    const float* __restrict__ pw, float* __restrict__ wqk_t,
    float* __restrict__ p_t)
{
    const int i = blockIdx.x * 256 + threadIdx.x;
    if (i < C_DIM * 512) {
        const int k = i >> 9, col = i & 511;
        const int h = col >> 6, j = col & 63;
        wqk_t[i] = (j < 32) ? qw[(size_t)(h * 32 + j) * C_DIM + k]
                            : kw[(size_t)(h * 32 + j - 32) * C_DIM + k];
    } else {
        const int i2 = i - C_DIM * 512;            // < 65536
        const int k = i2 >> 8, c = i2 & 255;
        p_t[i2] = pw[(size_t)c * C_DIM + k];
    }
}

// K1: 2 heads per block. grid (NHEAD/2, N/128, B), block 256.
// Block tile m=128 (h0:q0-31,k0-31 | h1:q0-31,k0-31), n=128, BK=32.
// Thread tile 8 rows x 8 cols.
__global__ __launch_bounds__(256, 3) void k_qk(
    const float* __restrict__ x, const float* __restrict__ wqk,   // [256][512]
    const float* __restrict__ qg, const float* __restrict__ qbeta,
    const float* __restrict__ qmean, const float* __restrict__ qvar,
    const float* __restrict__ kg, const float* __restrict__ kbeta,
    const float* __restrict__ kmean, const float* __restrict__ kvar,
    uint32_t* __restrict__ xbits)
{
    __shared__ float w_lds[32 * 128];   // [k][m] 16 KB
    __shared__ float x_lds[32 * 128];   // [k][n] 16 KB
    __shared__ float inv_lds[128];
    __shared__ float bias_lds[128];
    // epilogue scratch aliased onto x_lds (free after last chunk's compute+barrier)
    float*    qsum_lds = x_lds;                     // [hsel][col] 256 f
    float*    attn_lds = x_lds + 256;               // [hsel][col] 256 f
    uint32_t* pack_lds = (uint32_t*)(x_lds + 512);  // [hsel][krow][word] 256 w

    const int tid = threadIdx.x;
    const int hp = blockIdx.x, nt = blockIdx.y, b = blockIdx.z;
    const int n0g = nt * 128;

    const int  mg   = tid >> 4;        // 0..15 -> rows mg*8..+7
    const int  m0   = mg << 3;
    const int  ng   = tid & 15;
    const int  n0   = ng << 2;         // col quad A; quad B = 64+n0
    const int  hsel = mg >> 3;         // head within pair
    const bool is_q = ((mg & 7) < 4);  // wave-uniform (4 mg per wave)

    // BN consts -> LDS (once)
    if (tid < 128) {
        const int m = tid;
        const int hs = m >> 6, j = m & 63;
        const int h = hp * 2 + hs;
        const bool q = (j < 32);
        const float* g  = q ? qg    : kg;
        const float* be = q ? qbeta : kbeta;
        const float* me = q ? qmean : kmean;
        const float* va = q ? qvar  : kvar;
        const int ch = h * DHEAD + (q ? j : j - 32);
        const float iv = __fdiv_rn(g[ch], __fsqrt_rn(__fadd_rn(va[ch], 1e-5f)));
        inv_lds[m]  = iv;
        bias_lds[m] = __fsub_rn(be[ch], __fmul_rn(me[ch], iv));
    }

    // staging: round r covers k-rows r*8 + (tid>>5), cols (tid&31)*4..+3
    // LDS flat dst = r*1024 + tid*4 (wave-uniform base + lane*16B)
    const int skl  = tid >> 5;
    const int scol = (tid & 31) << 2;
    const float* wgp = wqk + (size_t)skl * 512 + hp * 128 + scol;

    float vstate[64];
    #pragma unroll
    for (int i = 0; i < 64; i++) vstate[i] = 0.0f;
    float v_attn = 0.0f;               // one (head,col) attn state per thread

    for (int t = 0; t < T_DIM; ++t) {
        float acc[64];
        #pragma unroll
        for (int i = 0; i < 64; i++) acc[i] = 0.0f;

        const float* xgp = x + ((size_t)(t * B_DIM + b) * C_DIM + skl) * N_DIM
                           + n0g + scol;

        for (int c = 0; c < 8; ++c) {
            const int kk = c * 32;
            __syncthreads();   // prev chunk readers / epilogue scratch readers done
            #pragma unroll
            for (int r = 0; r < 4; r++) {
                async_copy16(wgp + (size_t)(kk + r * 8) * 512, w_lds + r * 1024 + tid * 4);
                async_copy16(xgp + (size_t)(kk + r * 8) * N_DIM, x_lds + r * 1024 + tid * 4);
            }
            __syncthreads();   // drain
            #pragma unroll 2
            for (int k = 0; k < 32; k++) {
                const float4 a0 = *(const float4*)(w_lds + k * 128 + m0);
                const float4 a1 = *(const float4*)(w_lds + k * 128 + m0 + 4);
                const float4 b0 = *(const float4*)(x_lds + k * 128 + n0);
                const float4 b1 = *(const float4*)(x_lds + k * 128 + 64 + n0);
                FMA_8x8()
            }
        }

        // BN + LIF; spikes overwrite acc
        #pragma unroll
        for (int r = 0; r < 8; r++) {
            const float iv = inv_lds[m0 + r];
            const float bs = bias_lds[m0 + r];
            #pragma unroll
            for (int j = 0; j < 8; j++) {
                const float y = __fadd_rn(__fmul_rn(acc[r * 8 + j], iv), bs);
                acc[r * 8 + j] = lif_step(vstate[r * 8 + j], y, 1.0f);
            }
        }

        __syncthreads();   // FMA readers done -> x_lds reusable as scratch
        qsum_lds[tid] = 0.0f;
        pack_lds[tid] = 0u;
        __syncthreads();

        if (is_q) {   // head-sum of q spikes (integer-valued -> exact any order)
            #pragma unroll
            for (int j = 0; j < 8; j++) {
                const int col = (j < 4) ? (n0 + j) : (64 + n0 + (j - 4));
                float cs = acc[j];
                #pragma unroll
                for (int r = 1; r < 8; r++) cs += acc[r * 8 + j];
                atomicAdd(&qsum_lds[hsel * 128 + col], cs);
            }
        }
        __syncthreads();
        attn_lds[tid] = lif_step(v_attn, qsum_lds[tid], 0.5f);
        __syncthreads();

        if (!is_q) {  // x_one = attn * k_spikes, bit-packed
            #pragma unroll
            for (int r = 0; r < 8; r++) {
                const int krow = ((mg & 7) - 4) * 8 + r;   // 0..31
                #pragma unroll
                for (int ci = 0; ci < 2; ci++) {
                    uint32_t nib = 0;
                    #pragma unroll
                    for (int jj = 0; jj < 4; jj++) {
                        const int col = ci * 64 + n0 + jj;
                        if (acc[r * 8 + ci * 4 + jj] != 0.0f &&
                            attn_lds[hsel * 128 + col] != 0.0f)
                            nib |= (1u << jj);
                    }
                    if (nib) {
                        const int word = ci * 2 + (ng >> 3);
                        const int shf  = (ng & 7) * 4;
                        atomicOr(&pack_lds[hsel * 128 + krow * 4 + word], nib << shf);
                    }
                }
            }
        }
        __syncthreads();
        {   // write out: one word per thread
            const int hs2  = tid >> 7;
            const int rem  = tid & 127;
            const int krow = rem >> 2, word = rem & 3;
            const int ch = (hp * 2 + hs2) * DHEAD + krow;
            xbits[((size_t)(t * B_DIM + b) * C_DIM + ch) * NWRD + nt * 4 + word]
                = pack_lds[tid];
        }
        // next t's chunk-0 barrier protects scratch readers
    }
}

// K2: projection GEMM. grid (C/128, N/128, B), block 256.
// Block tile m=128, n=128, BK=32; thread tile 8x8. Bit input unpacked to LDS;
// next chunk's bit-word prefetched during FMA.
__global__ __launch_bounds__(256, 3) void k_proj(
    const uint32_t* __restrict__ xbits, const float* __restrict__ pt,  // [256][256]
    const float* __restrict__ pbias, const float* __restrict__ pg,
    const float* __restrict__ pbeta, const float* __restrict__ pmean,
    const float* __restrict__ pvar, float* __restrict__ out)
{
    __shared__ float w_lds[32 * 128];
    __shared__ float x_lds[32 * 128];
    __shared__ float inv_lds[128];
    __shared__ float bias_lds[128];
    __shared__ float pb_lds[128];

    const int tid = threadIdx.x;
    const int mt = blockIdx.x, nt = blockIdx.y, b = blockIdx.z;
    const int n0g = nt * 128;
    const int c0  = mt * 128;

    const int mg = tid >> 4, m0 = mg << 3;
    const int ng = tid & 15, n0 = ng << 2;

    if (tid < 128) {
        const int ch = c0 + tid;
        const float iv = __fdiv_rn(pg[ch], __fsqrt_rn(__fadd_rn(pvar[ch], 1e-5f)));
        inv_lds[tid]  = iv;
        bias_lds[tid] = __fsub_rn(pbeta[ch], __fmul_rn(pmean[ch], iv));
        pb_lds[tid]   = pbias[ch];
    }

    const int skl  = tid >> 5;
    const int scol = (tid & 31) << 2;
    const float* wgp = pt + (size_t)skl * 256 + c0 + scol;

    // unpack geometry: thread -> k-row urow (0..31), 16 cols at cg*16
    const int urow = tid >> 3, cg = tid & 7;
    const int wsel = nt * 4 + (cg >> 1);
    const int ushf = (cg & 1) * 16;
    float* xw = x_lds + tid * 16;      // = urow*128 + cg*16

    float vstate[64];
    #pragma unroll
    for (int i = 0; i < 64; i++) vstate[i] = 0.0f;

    for (int t = 0; t < T_DIM; ++t) {
        float acc[64];
        #pragma unroll
        for (int i = 0; i < 64; i++) acc[i] = 0.0f;

        const uint32_t* xg = xbits + (size_t)(t * B_DIM + b) * C_DIM * NWRD;

        uint32_t u = xg[(size_t)urow * NWRD + wsel];   // chunk 0 bits

        for (int c = 0; c < 8; ++c) {
            __syncthreads();   // prev chunk readers done
            {   // unpack 16 bits -> 16 floats (4x ds_write_b128, lane-contiguous)
                const uint32_t bits = (u >> ushf) & 0xffffu;
                #pragma unroll
                for (int q4 = 0; q4 < 4; q4++) {
                    float4 f;
                    f.x = ((bits >> (q4 * 4 + 0)) & 1u) ? 1.0f : 0.0f;
                    f.y = ((bits >> (q4 * 4 + 1)) & 1u) ? 1.0f : 0.0f;
                    f.z = ((bits >> (q4 * 4 + 2)) & 1u) ? 1.0f : 0.0f;
                    f.w = ((bits >> (q4 * 4 + 3)) & 1u) ? 1.0f : 0.0f;
                    *(float4*)(xw + q4 * 4) = f;
                }
            }
            #pragma unroll
            for (int r = 0; r < 4; r++)
                async_copy16(wgp + (size_t)(c * 32 + r * 8) * 256,
                             w_lds + r * 1024 + tid * 4);
            __syncthreads();   // drain lgkm (unpack) + vmcnt (w stage)
            if (c + 1 < 8)     // prefetch next chunk's bits; FMA hides latency
                u = xg[(size_t)((c + 1) * 32 + urow) * NWRD + wsel];
            #pragma unroll 2
            for (int k = 0; k < 32; k++) {
                const float4 a0 = *(const float4*)(w_lds + k * 128 + m0);
                const float4 a1 = *(const float4*)(w_lds + k * 128 + m0 + 4);
                const float4 b0 = *(const float4*)(x_lds + k * 128 + n0);
                const float4 b1 = *(const float4*)(x_lds + k * 128 + 64 + n0);
                FMA_8x8()
            }
        }

        #pragma unroll
        for (int r = 0; r < 8; r++) {
            const int ch = c0 + m0 + r;
            const float iv = inv_lds[m0 + r];
            const float bs = bias_lds[m0 + r];
            const float pb = pb_lds[m0 + r];
            float* ob = out + ((size_t)(t * B_DIM + b) * C_DIM + ch) * N_DIM + n0g;
            float oAv[4], oBv[4];
            #pragma unroll
            for (int j = 0; j < 8; j++) {
                float y = __fadd_rn(acc[r * 8 + j], pb);
                y = __fadd_rn(__fmul_rn(y, iv), bs);
                const float s = lif_step(vstate[r * 8 + j], y, 1.0f);
                if (j < 4) oAv[j] = s; else oBv[j - 4] = s;
            }
            float4 oA, oB;
            oA.x = oAv[0]; oA.y = oAv[1]; oA.z = oAv[2]; oA.w = oAv[3];
            oB.x = oBv[0]; oB.y = oBv[1]; oB.z = oBv[2]; oB.w = oBv[3];
            *(float4*)(ob + n0)      = oA;
            *(float4*)(ob + 64 + n0) = oB;
        }
    }
}

extern "C" void kernel_launch(void* const* d_in, const int* in_sizes, int n_in,
                              void* d_out, int out_size, void* d_ws, size_t ws_size,
                              hipStream_t stream) {
    const float* x    = (const float*)d_in[0];
    const float* q_w  = (const float*)d_in[1];
    const float* q_g  = (const float*)d_in[2];
    const float* q_b  = (const float*)d_in[3];
    const float* q_m  = (const float*)d_in[4];
    const float* q_v  = (const float*)d_in[5];
    const float* k_w  = (const float*)d_in[6];
    const float* k_g  = (const float*)d_in[7];
    const float* k_b  = (const float*)d_in[8];
    const float* k_m  = (const float*)d_in[9];
    const float* k_v  = (const float*)d_in[10];
    const float* p_w  = (const float*)d_in[11];
    const float* p_b  = (const float*)d_in[12];
    const float* p_g  = (const float*)d_in[13];
    const float* p_be = (const float*)d_in[14];
    const float* p_m  = (const float*)d_in[15];
    const float* p_v  = (const float*)d_in[16];

    // ws layout: wqk_t 512KB | p_t 256KB | xbits 4MB
    float*    wqk_t = (float*)d_ws;
    float*    p_t   = (float*)((char*)d_ws + 524288);
    uint32_t* xbits = (uint32_t*)((char*)d_ws + 786432);
    float*    out   = (float*)d_out;

    k_transpose<<<768, 256, 0, stream>>>(q_w, k_w, p_w, wqk_t, p_t);

    dim3 g1(NHEAD / 2, N_DIM / 128, B_DIM);
    k_qk<<<g1, 256, 0, stream>>>(x, wqk_t, q_g, q_b, q_m, q_v,
                                 k_g, k_b, k_m, k_v, xbits);

    dim3 g2(C_DIM / 128, N_DIM / 128, B_DIM);
    k_proj<<<g2, 256, 0, stream>>>(xbits, p_t, p_b, p_g, p_be, p_m, p_v, out);
}

// Round 6
// 825.938 us; speedup vs baseline: 1.2375x; 1.0037x over previous
//
#include <hip/hip_runtime.h>
#include <cstdint>
#include <cstddef>

#define T_DIM 4
#define B_DIM 32
#define C_DIM 256
#define N_DIM 1024
#define NHEAD 8
#define DHEAD 32
#define NWRD 32   // N/32 bit-words per row

// LIF step, exact reference rounding: v += (x-v)/2; s = v>=vth; hard reset.
__device__ __forceinline__ float lif_step(float& v, float x, float vth) {
    v = __fadd_rn(v, __fmul_rn(__fsub_rn(x, v), 0.5f));
    const float s = (v >= vth) ? 1.0f : 0.0f;
    if (s != 0.0f) v = 0.0f;
    return s;
}

// async global->LDS, 16B per lane. LDS dest = wave-uniform base + lane*16.
__device__ __forceinline__ void async_copy16(const float* g, float* l) {
    __builtin_amdgcn_global_load_lds(
        (const __attribute__((address_space(1))) unsigned int*)g,
        (__attribute__((address_space(3))) unsigned int*)l, 16, 0, 0);
}

// one a-element times 8 cols (two float4 col-quads), strict k-ascending chains
#define FMA_ROW(r, av)                                \
    acc[(r)*8+0] = fmaf(av, b0.x, acc[(r)*8+0]);      \
    acc[(r)*8+1] = fmaf(av, b0.y, acc[(r)*8+1]);      \
    acc[(r)*8+2] = fmaf(av, b0.z, acc[(r)*8+2]);      \
    acc[(r)*8+3] = fmaf(av, b0.w, acc[(r)*8+3]);      \
    acc[(r)*8+4] = fmaf(av, b1.x, acc[(r)*8+4]);      \
    acc[(r)*8+5] = fmaf(av, b1.y, acc[(r)*8+5]);      \
    acc[(r)*8+6] = fmaf(av, b1.z, acc[(r)*8+6]);      \
    acc[(r)*8+7] = fmaf(av, b1.w, acc[(r)*8+7]);

#define FMA_8x8()        \
    FMA_ROW(0, a0.x)     \
    FMA_ROW(1, a0.y)     \
    FMA_ROW(2, a0.z)     \
    FMA_ROW(3, a0.w)     \
    FMA_ROW(4, a1.x)     \
    FMA_ROW(5, a1.y)     \
    FMA_ROW(6, a1.z)     \
    FMA_ROW(7, a1.w)

// Pre-transpose: wqk_t[k][h*64+j] = (j<32 ? qw[h*32+j][k] : kw[h*32+j-32][k])
//                p_t[k][c] = pw[c][k]
__global__ __launch_bounds__(256) void k_transpose(
    const float* __restrict__ qw, const float* __restrict__ kw,
    const float* __restrict__ pw, float* __restrict__ wqk_t,
    float* __restrict__ p_t)
{
    const int i = blockIdx.x * 256 + threadIdx.x;
    if (i < C_DIM * 512) {
        const int k = i >> 9, col = i & 511;
        const int h = col >> 6, j = col & 63;
        wqk_t[i] = (j < 32) ? qw[(size_t)(h * 32 + j) * C_DIM + k]
                            : kw[(size_t)(h * 32 + j - 32) * C_DIM + k];
    } else {
        const int i2 = i - C_DIM * 512;            // < 65536
        const int k = i2 >> 8, c = i2 & 255;
        p_t[i2] = pw[(size_t)c * C_DIM + k];
    }
}

// K1: 2 heads per block. grid (NHEAD/2, N/128, B), block 256.
// Block tile m=128, n=128, BK=32; thread tile 8x8. Double-buffered w+x via
// global_load_lds; ONE barrier per chunk (drain waits copies issued a full
// compute-phase earlier). 32 global chunks = 4 t x 8 k-chunks.
__global__ __launch_bounds__(256, 2) void k_qk(
    const float* __restrict__ x, const float* __restrict__ wqk,   // [256][512]
    const float* __restrict__ qg, const float* __restrict__ qbeta,
    const float* __restrict__ qmean, const float* __restrict__ qvar,
    const float* __restrict__ kg, const float* __restrict__ kbeta,
    const float* __restrict__ kmean, const float* __restrict__ kvar,
    uint32_t* __restrict__ xbits)
{
    __shared__ float w_lds[2][32 * 128];   // [buf][k][m] 2x16 KB
    __shared__ float x_lds[2][32 * 128];   // [buf][k][n] 2x16 KB
    __shared__ float inv_lds[128];
    __shared__ float bias_lds[128];
    __shared__ float    qsum_lds[256];     // dedicated epilogue scratch
    __shared__ float    attn_lds[256];
    __shared__ uint32_t pack_lds[256];

    const int tid = threadIdx.x;
    const int hp = blockIdx.x, nt = blockIdx.y, b = blockIdx.z;
    const int n0g = nt * 128;

    const int  mg   = tid >> 4;        // 0..15 -> rows mg*8..+7
    const int  m0   = mg << 3;
    const int  ng   = tid & 15;
    const int  n0   = ng << 2;         // col quad A; quad B = 64+n0
    const int  hsel = mg >> 3;
    const bool is_q = ((mg & 7) < 4);  // wave-uniform

    if (tid < 128) {
        const int m = tid;
        const int hs = m >> 6, j = m & 63;
        const int h = hp * 2 + hs;
        const bool q = (j < 32);
        const float* g  = q ? qg    : kg;
        const float* be = q ? qbeta : kbeta;
        const float* me = q ? qmean : kmean;
        const float* va = q ? qvar  : kvar;
        const int ch = h * DHEAD + (q ? j : j - 32);
        const float iv = __fdiv_rn(g[ch], __fsqrt_rn(__fadd_rn(va[ch], 1e-5f)));
        inv_lds[m]  = iv;
        bias_lds[m] = __fsub_rn(be[ch], __fmul_rn(me[ch], iv));
    }

    // staging: round r covers k-row r*8 + skl, cols scol..+3; dst = r*1024 + tid*4
    const int skl  = tid >> 5;
    const int scol = (tid & 31) << 2;
    const float* wgp = wqk + (size_t)skl * 512 + hp * 128 + scol;

    float vstate[64];
    #pragma unroll
    for (int i = 0; i < 64; i++) vstate[i] = 0.0f;
    float v_attn = 0.0f;

    // stage chunk 0 into buf 0
    {
        const float* xgp = x + ((size_t)b * C_DIM + skl) * N_DIM + n0g + scol;
        #pragma unroll
        for (int r = 0; r < 4; r++) {
            async_copy16(wgp + (size_t)(r * 8) * 512,  &w_lds[0][r * 1024 + tid * 4]);
            async_copy16(xgp + (size_t)(r * 8) * N_DIM, &x_lds[0][r * 1024 + tid * 4]);
        }
    }

    float acc[64];
    #pragma unroll
    for (int i = 0; i < 64; i++) acc[i] = 0.0f;

    for (int g = 0; g < 32; ++g) {
        const int cur = g & 1;
        __syncthreads();   // drains stage(g) (in flight a full compute phase);
                           // joins readers of buf[1-cur] (chunk g-1)
        if (g + 1 < 32) {  // stage chunk g+1 into the other buffer
            const int g1 = g + 1, tt = g1 >> 3, kk = (g1 & 7) * 32;
            const float* xgp = x + ((size_t)(tt * B_DIM + b) * C_DIM + kk + skl) * N_DIM
                               + n0g + scol;
            float* wd = &w_lds[1 - cur][0];
            float* xd = &x_lds[1 - cur][0];
            #pragma unroll
            for (int r = 0; r < 4; r++) {
                async_copy16(wgp + (size_t)(kk + r * 8) * 512,  wd + r * 1024 + tid * 4);
                async_copy16(xgp + (size_t)(r * 8) * N_DIM,     xd + r * 1024 + tid * 4);
            }
        }
        {
            const float* wl = &w_lds[cur][0];
            const float* xl = &x_lds[cur][0];
            #pragma unroll 2
            for (int k = 0; k < 32; k++) {
                const float4 a0 = *(const float4*)(wl + k * 128 + m0);
                const float4 a1 = *(const float4*)(wl + k * 128 + m0 + 4);
                const float4 b0 = *(const float4*)(xl + k * 128 + n0);
                const float4 b1 = *(const float4*)(xl + k * 128 + 64 + n0);
                FMA_8x8()
            }
        }

        if ((g & 7) == 7) {   // end of one t: BN + LIF + attn + pack epilogue
            const int t = g >> 3;
            #pragma unroll
            for (int r = 0; r < 8; r++) {
                const float iv = inv_lds[m0 + r];
                const float bs = bias_lds[m0 + r];
                #pragma unroll
                for (int j = 0; j < 8; j++) {
                    const float y = __fadd_rn(__fmul_rn(acc[r * 8 + j], iv), bs);
                    acc[r * 8 + j] = lif_step(vstate[r * 8 + j], y, 1.0f);
                }
            }
            qsum_lds[tid] = 0.0f;
            pack_lds[tid] = 0u;
            __syncthreads();
            if (is_q) {
                #pragma unroll
                for (int j = 0; j < 8; j++) {
                    const int col = (j < 4) ? (n0 + j) : (64 + n0 + (j - 4));
                    float cs = acc[j];
                    #pragma unroll
                    for (int r = 1; r < 8; r++) cs += acc[r * 8 + j];
                    atomicAdd(&qsum_lds[hsel * 128 + col], cs);
                }
            }
            __syncthreads();
            attn_lds[tid] = lif_step(v_attn, qsum_lds[tid], 0.5f);
            __syncthreads();
            if (!is_q) {
                #pragma unroll
                for (int r = 0; r < 8; r++) {
                    const int krow = ((mg & 7) - 4) * 8 + r;
                    #pragma unroll
                    for (int ci = 0; ci < 2; ci++) {
                        uint32_t nib = 0;
                        #pragma unroll
                        for (int jj = 0; jj < 4; jj++) {
                            const int col = ci * 64 + n0 + jj;
                            if (acc[r * 8 + ci * 4 + jj] != 0.0f &&
                                attn_lds[hsel * 128 + col] != 0.0f)
                                nib |= (1u << jj);
                        }
                        if (nib) {
                            const int word = ci * 2 + (ng >> 3);
                            const int shf  = (ng & 7) * 4;
                            atomicOr(&pack_lds[hsel * 128 + krow * 4 + word], nib << shf);
                        }
                    }
                }
            }
            __syncthreads();
            {
                const int hs2  = tid >> 7;
                const int rem  = tid & 127;
                const int krow = rem >> 2, word = rem & 3;
                const int ch = (hp * 2 + hs2) * DHEAD + krow;
                xbits[((size_t)(t * B_DIM + b) * C_DIM + ch) * NWRD + nt * 4 + word]
                    = pack_lds[tid];
            }
            // reset acc for next t (registers)
            #pragma unroll
            for (int i = 0; i < 64; i++) acc[i] = 0.0f;
            // next loop-top barrier protects scratch before next epilogue
        }
    }
}

// K2: projection GEMM. grid (C/128, N/128, B), block 256.
// Block tile m=128, n=128, BK=32; thread tile 8x8. Double-buffered w (async)
// + x (bit-unpack to LDS); bits pipelined 2 chunks ahead in a register.
// ONE barrier per chunk; epilogue uses no LDS (no barriers).
__global__ __launch_bounds__(256, 2) void k_proj(
    const uint32_t* __restrict__ xbits, const float* __restrict__ pt,  // [256][256]
    const float* __restrict__ pbias, const float* __restrict__ pg,
    const float* __restrict__ pbeta, const float* __restrict__ pmean,
    const float* __restrict__ pvar, float* __restrict__ out)
{
    __shared__ float w_lds[2][32 * 128];
    __shared__ float x_lds[2][32 * 128];
    __shared__ float inv_lds[128];
    __shared__ float bias_lds[128];
    __shared__ float pb_lds[128];

    const int tid = threadIdx.x;
    const int mt = blockIdx.x, nt = blockIdx.y, b = blockIdx.z;
    const int n0g = nt * 128;
    const int c0  = mt * 128;

    const int mg = tid >> 4, m0 = mg << 3;
    const int ng = tid & 15, n0 = ng << 2;

    if (tid < 128) {
        const int ch = c0 + tid;
        const float iv = __fdiv_rn(pg[ch], __fsqrt_rn(__fadd_rn(pvar[ch], 1e-5f)));
        inv_lds[tid]  = iv;
        bias_lds[tid] = __fsub_rn(pbeta[ch], __fmul_rn(pmean[ch], iv));
        pb_lds[tid]   = pbias[ch];
    }

    const int skl  = tid >> 5;
    const int scol = (tid & 31) << 2;
    const float* wgp = pt + (size_t)skl * 256 + c0 + scol;

    // unpack: thread -> chunk k-row urow (0..31), 16 cols at cg*16
    const int urow = tid >> 3, cg = tid & 7;
    const int wsel = nt * 4 + (cg >> 1);
    const int ushf = (cg & 1) * 16;

    float vstate[64];
    #pragma unroll
    for (int i = 0; i < 64; i++) vstate[i] = 0.0f;

    // bits word for global chunk G: xbits[((G>>3)*B+b)*C*NWRD + ((G&7)*32+urow)*NWRD + wsel]
    #define BITS_AT(G) xbits[((size_t)((G) >> 3) * B_DIM + b) * C_DIM * NWRD \
                             + (size_t)(((G) & 7) * 32 + urow) * NWRD + wsel]

    // prologue: unpack chunk 0 + stage w(0) into buf0; preload bits(1)
    {
        const uint32_t u0 = BITS_AT(0);
        const uint32_t bits = (u0 >> ushf) & 0xffffu;
        float* xw = &x_lds[0][tid * 16];
        #pragma unroll
        for (int q4 = 0; q4 < 4; q4++) {
            float4 f;
            f.x = ((bits >> (q4 * 4 + 0)) & 1u) ? 1.0f : 0.0f;
            f.y = ((bits >> (q4 * 4 + 1)) & 1u) ? 1.0f : 0.0f;
            f.z = ((bits >> (q4 * 4 + 2)) & 1u) ? 1.0f : 0.0f;
            f.w = ((bits >> (q4 * 4 + 3)) & 1u) ? 1.0f : 0.0f;
            *(float4*)(xw + q4 * 4) = f;
        }
        #pragma unroll
        for (int r = 0; r < 4; r++)
            async_copy16(wgp + (size_t)(r * 8) * 256, &w_lds[0][r * 1024 + tid * 4]);
    }
    uint32_t u_a = BITS_AT(1);

    float acc[64];
    #pragma unroll
    for (int i = 0; i < 64; i++) acc[i] = 0.0f;

    for (int g = 0; g < 32; ++g) {
        const int cur = g & 1;
        __syncthreads();   // drains unpack writes + w copies for chunk g;
                           // joins readers of buf[1-cur]
        if (g + 1 < 32) {  // prepare chunk g+1 in the other buffer
            const int kk = ((g + 1) & 7) * 32;
            const uint32_t bits = (u_a >> ushf) & 0xffffu;
            float* xw = &x_lds[1 - cur][tid * 16];
            #pragma unroll
            for (int q4 = 0; q4 < 4; q4++) {
                float4 f;
                f.x = ((bits >> (q4 * 4 + 0)) & 1u) ? 1.0f : 0.0f;
                f.y = ((bits >> (q4 * 4 + 1)) & 1u) ? 1.0f : 0.0f;
                f.z = ((bits >> (q4 * 4 + 2)) & 1u) ? 1.0f : 0.0f;
                f.w = ((bits >> (q4 * 4 + 3)) & 1u) ? 1.0f : 0.0f;
                *(float4*)(xw + q4 * 4) = f;
            }
            float* wd = &w_lds[1 - cur][0];
            #pragma unroll
            for (int r = 0; r < 4; r++)
                async_copy16(wgp + (size_t)(kk + r * 8) * 256, wd + r * 1024 + tid * 4);
        }
        if (g + 2 < 32) u_a = BITS_AT(g + 2);   // hidden under compute(g)
        {
            const float* wl = &w_lds[cur][0];
            const float* xl = &x_lds[cur][0];
            #pragma unroll 2
            for (int k = 0; k < 32; k++) {
                const float4 a0 = *(const float4*)(wl + k * 128 + m0);
                const float4 a1 = *(const float4*)(wl + k * 128 + m0 + 4);
                const float4 b0 = *(const float4*)(xl + k * 128 + n0);
                const float4 b1 = *(const float4*)(xl + k * 128 + 64 + n0);
                FMA_8x8()
            }
        }

        if ((g & 7) == 7) {   // end of t: BN + LIF + store (registers + global only)
            const int t = g >> 3;
            #pragma unroll
            for (int r = 0; r < 8; r++) {
                const int ch = c0 + m0 + r;
                const float iv = inv_lds[m0 + r];
                const float bs = bias_lds[m0 + r];
                const float pb = pb_lds[m0 + r];
                float* ob = out + ((size_t)(t * B_DIM + b) * C_DIM + ch) * N_DIM + n0g;
                float oAv[4], oBv[4];
                #pragma unroll
                for (int j = 0; j < 8; j++) {
                    float y = __fadd_rn(acc[r * 8 + j], pb);
                    y = __fadd_rn(__fmul_rn(y, iv), bs);
                    const float s = lif_step(vstate[r * 8 + j], y, 1.0f);
                    if (j < 4) oAv[j] = s; else oBv[j - 4] = s;
                }
                float4 oA, oB;
                oA.x = oAv[0]; oA.y = oAv[1]; oA.z = oAv[2]; oA.w = oAv[3];
                oB.x = oBv[0]; oB.y = oBv[1]; oB.z = oBv[2]; oB.w = oBv[3];
                *(float4*)(ob + n0)      = oA;
                *(float4*)(ob + 64 + n0) = oB;
            }
            #pragma unroll
            for (int i = 0; i < 64; i++) acc[i] = 0.0f;
        }
    }
    #undef BITS_AT
}

extern "C" void kernel_launch(void* const* d_in, const int* in_sizes, int n_in,
                              void* d_out, int out_size, void* d_ws, size_t ws_size,
                              hipStream_t stream) {
    const float* x    = (const float*)d_in[0];
    const float* q_w  = (const float*)d_in[1];
    const float* q_g  = (const float*)d_in[2];
    const float* q_b  = (const float*)d_in[3];
    const float* q_m  = (const float*)d_in[4];
    const float* q_v  = (const float*)d_in[5];
    const float* k_w  = (const float*)d_in[6];
    const float* k_g  = (const float*)d_in[7];
    const float* k_b  = (const float*)d_in[8];
    const float* k_m  = (const float*)d_in[9];
    const float* k_v  = (const float*)d_in[10];
    const float* p_w  = (const float*)d_in[11];
    const float* p_b  = (const float*)d_in[12];
    const float* p_g  = (const float*)d_in[13];
    const float* p_be = (const float*)d_in[14];
    const float* p_m  = (const float*)d_in[15];
    const float* p_v  = (const float*)d_in[16];

    // ws layout: wqk_t 512KB | p_t 256KB | xbits 4MB
    float*    wqk_t = (float*)d_ws;
    float*    p_t   = (float*)((char*)d_ws + 524288);
    uint32_t* xbits = (uint32_t*)((char*)d_ws + 786432);
    float*    out   = (float*)d_out;

    k_transpose<<<768, 256, 0, stream>>>(q_w, k_w, p_w, wqk_t, p_t);

    dim3 g1(NHEAD / 2, N_DIM / 128, B_DIM);
    k_qk<<<g1, 256, 0, stream>>>(x, wqk_t, q_g, q_b, q_m, q_v,
                                 k_g, k_b, k_m, k_v, xbits);

    dim3 g2(C_DIM / 128, N_DIM / 128, B_DIM);
    k_proj<<<g2, 256, 0, stream>>>(xbits, p_t, p_b, p_g, p_be, p_m, p_v, out);
}